// Round 8
// baseline (34.084 us; speedup 1.0000x reference)
//
#include <hip/hip_runtime.h>

typedef float f2 __attribute__((ext_vector_type(2)));
typedef float f4 __attribute__((ext_vector_type(4)));
typedef int   i4 __attribute__((ext_vector_type(4)));

#define HIDDEN 64
#define MASK_FILL -1e9f
#define EPT 4  // edges per thread

// Round-6 kernel, unchanged. This round's experiment is in kernel_launch:
// the SAME kernel is launched twice back-to-back to measure marginal kernel
// cost vs fixed per-replay overhead (dur_2x - dur_1x = true kernel time).
__global__ __launch_bounds__(256) void edge_score_fused(
    const float* __restrict__ x,                 // [N,1]
    const int* __restrict__ edge_index,          // [2,E] int32
    const float* __restrict__ edge_attr,         // [E,2]
    const int* __restrict__ edge_mask,           // [E] int32
    const float* __restrict__ W1,                // [4,64]
    const float* __restrict__ b1,                // [64]
    const float* __restrict__ W2,                // [64,64]
    const float* __restrict__ b2,                // [64]
    const float* __restrict__ Ws,                // [64,1]
    const float* __restrict__ bs,                // [1]
    float* __restrict__ out, int E)
{
    __shared__ f4 wA[32], wB[32], wC[32];
    __shared__ float cS;

    const int t = threadIdx.x;

    // ---------- prologue: fold weights into LDS ----------
    {
        const f4* W2v = reinterpret_cast<const f4*>(W2 + t * 16);
        const int j0 = 16 * (t & 3);
        float p = 0.f;
#pragma unroll
        for (int i = 0; i < 4; ++i) {
            const f4 wv = W2v[i];
            const int j = j0 + 4 * i;
            p = fmaf(wv.x, Ws[j], p);
            p = fmaf(wv.y, Ws[j + 1], p);
            p = fmaf(wv.z, Ws[j + 2], p);
            p = fmaf(wv.w, Ws[j + 3], p);
        }
        p += __shfl_xor(p, 1);
        p += __shfl_xor(p, 2);
        if ((t & 3) == 0) {
            const int k = t >> 2;
            reinterpret_cast<float*>(&wC[k >> 1])[2 + (k & 1)] = p;  // v
        }
    }
    if (t < 32) {
        wA[t] = (f4){W1[2 * t], W1[2 * t + 1], W1[64 + 2 * t], W1[64 + 2 * t + 1]};
        wB[t] = (f4){W1[128 + 2 * t], W1[128 + 2 * t + 1], W1[192 + 2 * t], W1[192 + 2 * t + 1]};
    } else if (t >= 64 && t < 128) {
        const int l = t - 64;
        float p = b2[l] * Ws[l];
#pragma unroll
        for (int off = 1; off < 64; off <<= 1) p += __shfl_xor(p, off);
        if (l == 0) cS = p + bs[0];
    } else if (t >= 192) {
        const int k = t - 192;  // b1
        reinterpret_cast<float*>(&wC[k >> 1])[k & 1] = b1[k];
    }
    __syncthreads();

    // ---------- main: 4 edges / thread ----------
    const int tid = blockIdx.x * 256 + t;
    const int e = tid * EPT;
    if (e >= E) return;

    const i4 rows = __builtin_nontemporal_load(reinterpret_cast<const i4*>(edge_index + e));
    const i4 cols = __builtin_nontemporal_load(reinterpret_cast<const i4*>(edge_index + E + e));
    const i4 mk   = __builtin_nontemporal_load(reinterpret_cast<const i4*>(edge_mask + e));
    const f4 eaA  = __builtin_nontemporal_load(reinterpret_cast<const f4*>(edge_attr + 2 * e));
    const f4 eaB  = __builtin_nontemporal_load(reinterpret_cast<const f4*>(edge_attr + 2 * e + 4));

    const f2 xr0 = {x[rows.x], x[rows.x]}, xr1 = {x[rows.y], x[rows.y]},
             xr2 = {x[rows.z], x[rows.z]}, xr3 = {x[rows.w], x[rows.w]};
    const f2 xc0 = {x[cols.x], x[cols.x]}, xc1 = {x[cols.y], x[cols.y]},
             xc2 = {x[cols.z], x[cols.z]}, xc3 = {x[cols.w], x[cols.w]};
    const f2 e00 = {eaA.x, eaA.x}, e10 = {eaA.y, eaA.y};
    const f2 e01 = {eaA.z, eaA.z}, e11 = {eaA.w, eaA.w};
    const f2 e02 = {eaB.x, eaB.x}, e12 = {eaB.y, eaB.y};
    const f2 e03 = {eaB.z, eaB.z}, e13 = {eaB.w, eaB.w};

    const float c = cS;
    const f2 z2 = {0.f, 0.f};
    f2 a0 = {c, 0.f}, a1 = {c, 0.f}, a2 = {c, 0.f}, a3 = {c, 0.f};

#pragma unroll 4
    for (int k2 = 0; k2 < 32; ++k2) {
        const f4 A = wA[k2];   // ds_read_b128 broadcast
        const f4 B = wB[k2];
        const f4 C = wC[k2];
        const f2 w0 = {A.x, A.y}, w1 = {A.z, A.w};
        const f2 w2 = {B.x, B.y}, w3 = {B.z, B.w};
        const f2 bb = {C.x, C.y}, vv = {C.z, C.w};

        f2 h0 = __builtin_elementwise_fma(xr0, w0, __builtin_elementwise_fma(xc0, w1,
                __builtin_elementwise_fma(e00, w2, __builtin_elementwise_fma(e10, w3, bb))));
        f2 h1 = __builtin_elementwise_fma(xr1, w0, __builtin_elementwise_fma(xc1, w1,
                __builtin_elementwise_fma(e01, w2, __builtin_elementwise_fma(e11, w3, bb))));
        f2 h2 = __builtin_elementwise_fma(xr2, w0, __builtin_elementwise_fma(xc2, w1,
                __builtin_elementwise_fma(e02, w2, __builtin_elementwise_fma(e12, w3, bb))));
        f2 h3 = __builtin_elementwise_fma(xr3, w0, __builtin_elementwise_fma(xc3, w1,
                __builtin_elementwise_fma(e03, w2, __builtin_elementwise_fma(e13, w3, bb))));
        a0 = __builtin_elementwise_fma(__builtin_elementwise_max(h0, z2), vv, a0);
        a1 = __builtin_elementwise_fma(__builtin_elementwise_max(h1, z2), vv, a1);
        a2 = __builtin_elementwise_fma(__builtin_elementwise_max(h2, z2), vv, a2);
        a3 = __builtin_elementwise_fma(__builtin_elementwise_max(h3, z2), vv, a3);
    }

    f4 res;
    res.x = mk.x ? (a0.x + a0.y) : MASK_FILL;
    res.y = mk.y ? (a1.x + a1.y) : MASK_FILL;
    res.z = mk.z ? (a2.x + a2.y) : MASK_FILL;
    res.w = mk.w ? (a3.x + a3.y) : MASK_FILL;
    __builtin_nontemporal_store(res, reinterpret_cast<f4*>(out + e));
}

extern "C" void kernel_launch(void* const* d_in, const int* in_sizes, int n_in,
                              void* d_out, int out_size, void* d_ws, size_t ws_size,
                              hipStream_t stream) {
    const float* x          = (const float*)d_in[0];
    const int*   edge_index = (const int*)d_in[1];
    const float* edge_attr  = (const float*)d_in[2];
    const int*   edge_mask  = (const int*)d_in[3];
    const float* W1 = (const float*)d_in[4];
    const float* b1 = (const float*)d_in[5];
    const float* W2 = (const float*)d_in[6];
    const float* b2 = (const float*)d_in[7];
    const float* Ws = (const float*)d_in[8];
    const float* bs = (const float*)d_in[9];
    float* out = (float*)d_out;

    const int E = out_size;  // 1,000,000
    const int threads = 256;
    const int work = (E + EPT - 1) / EPT;
    const int blocks = (work + threads - 1) / threads;

    // PROBE: launch the identical kernel twice. Output is identical (idempotent);
    // dur_us(2x) - dur_us(1x from round 6) = marginal kernel cost, separating
    // fixed per-replay overhead from real kernel time.
    edge_score_fused<<<blocks, threads, 0, stream>>>(
        x, edge_index, edge_attr, edge_mask, W1, b1, W2, b2, Ws, bs, out, E);
    edge_score_fused<<<blocks, threads, 0, stream>>>(
        x, edge_index, edge_attr, edge_mask, W1, b1, W2, b2, Ws, bs, out, E);
}

// Round 9
// 19.417 us; speedup vs baseline: 1.7553x; 1.7553x over previous
//
#include <hip/hip_runtime.h>

typedef float f2 __attribute__((ext_vector_type(2)));
typedef float f4 __attribute__((ext_vector_type(4)));
typedef int   i4 __attribute__((ext_vector_type(4)));

#define HIDDEN 64
#define MASK_FILL -1e9f
#define EPT 4  // edges per thread

// scores = relu([x[row], x[col], edge_attr] @ W1 + b1) . v + c
// v = W2 @ Ws, c = b2.Ws + bs  (folded per-block in prologue).
// Weight path redesign (round 9): W1 read with wave-uniform affine indices
// directly from global -> compiler scalarizes to s_load (SMEM pipe).
// Only (b1, v) pairs stay in LDS: ONE ds_read_b128 per k-pair instead of
// three (DS pipe is per-CU shared -> was the dominant cost at 7.3 us/CU).
__global__ __launch_bounds__(256) void edge_score_fused(
    const float* __restrict__ x,                 // [N,1]
    const int* __restrict__ edge_index,          // [2,E] int32
    const float* __restrict__ edge_attr,         // [E,2]
    const int* __restrict__ edge_mask,           // [E] int32
    const float* __restrict__ W1,                // [4,64]
    const float* __restrict__ b1,                // [64]
    const float* __restrict__ W2,                // [64,64]
    const float* __restrict__ b2,                // [64]
    const float* __restrict__ Ws,                // [64,1]
    const float* __restrict__ bs,                // [1]
    float* __restrict__ out, int E)
{
    __shared__ f4 bvS[32];   // per k-pair: (b_lo, b_hi, v_lo, v_hi)
    __shared__ float cS;

    const int t = threadIdx.x;

    // ---------- prologue: fold v = W2@Ws, c = b2.Ws + bs ----------
    // 4 threads per W2 row, coalesced f4 reads, 4-lane shuffle reduce.
    {
        const f4* W2v = reinterpret_cast<const f4*>(W2 + t * 16);
        const int j0 = 16 * (t & 3);
        float p = 0.f;
#pragma unroll
        for (int i = 0; i < 4; ++i) {
            const f4 wv = W2v[i];
            const int j = j0 + 4 * i;
            p = fmaf(wv.x, Ws[j], p);
            p = fmaf(wv.y, Ws[j + 1], p);
            p = fmaf(wv.z, Ws[j + 2], p);
            p = fmaf(wv.w, Ws[j + 3], p);
        }
        p += __shfl_xor(p, 1);
        p += __shfl_xor(p, 2);
        if ((t & 3) == 0) {
            const int k = t >> 2;
            reinterpret_cast<float*>(&bvS[k >> 1])[2 + (k & 1)] = p;  // v_k
        }
    }
    if (t >= 64 && t < 128) {
        const int l = t - 64;
        float p = b2[l] * Ws[l];
#pragma unroll
        for (int off = 1; off < 64; off <<= 1) p += __shfl_xor(p, off);
        if (l == 0) cS = p + bs[0];
    } else if (t >= 192) {
        const int k = t - 192;  // b1 -> (b_lo, b_hi) halves
        reinterpret_cast<float*>(&bvS[k >> 1])[k & 1] = b1[k];
    }
    __syncthreads();

    // ---------- main: 4 edges / thread ----------
    const int tid = blockIdx.x * 256 + t;
    const int e = tid * EPT;
    if (e >= E) return;  // E % 4 == 0

    const i4 rows = *reinterpret_cast<const i4*>(edge_index + e);
    const i4 cols = *reinterpret_cast<const i4*>(edge_index + E + e);
    const i4 mk   = *reinterpret_cast<const i4*>(edge_mask + e);
    const f4 eaA  = *reinterpret_cast<const f4*>(edge_attr + 2 * e);
    const f4 eaB  = *reinterpret_cast<const f4*>(edge_attr + 2 * e + 4);

    // gathers (x = 200KB, L2-resident)
    const f2 xr0 = {x[rows.x], x[rows.x]}, xr1 = {x[rows.y], x[rows.y]},
             xr2 = {x[rows.z], x[rows.z]}, xr3 = {x[rows.w], x[rows.w]};
    const f2 xc0 = {x[cols.x], x[cols.x]}, xc1 = {x[cols.y], x[cols.y]},
             xc2 = {x[cols.z], x[cols.z]}, xc3 = {x[cols.w], x[cols.w]};
    const f2 e00 = {eaA.x, eaA.x}, e10 = {eaA.y, eaA.y};
    const f2 e01 = {eaA.z, eaA.z}, e11 = {eaA.w, eaA.w};
    const f2 e02 = {eaB.x, eaB.x}, e12 = {eaB.y, eaB.y};
    const f2 e03 = {eaB.z, eaB.z}, e13 = {eaB.w, eaB.w};

    const float c = cS;
    const f2 z2 = {0.f, 0.f};
    f2 a0 = {c, 0.f}, a1 = {c, 0.f}, a2 = {c, 0.f}, a3 = {c, 0.f};

#pragma unroll 4
    for (int k2 = 0; k2 < 32; ++k2) {
        // wave-uniform affine-indexed W1 reads -> SMEM s_load (no DS, no
        // divergent VMEM). Adjacent pairs merge into s_load_dwordx2/x4.
        const f2 w0 = {W1[2 * k2],       W1[2 * k2 + 1]};
        const f2 w1 = {W1[64 + 2 * k2],  W1[64 + 2 * k2 + 1]};
        const f2 w2 = {W1[128 + 2 * k2], W1[128 + 2 * k2 + 1]};
        const f2 w3 = {W1[192 + 2 * k2], W1[192 + 2 * k2 + 1]};
        const f4 C = bvS[k2];           // single broadcast ds_read_b128
        const f2 bb = {C.x, C.y}, vv = {C.z, C.w};

        f2 h0 = __builtin_elementwise_fma(xr0, w0, __builtin_elementwise_fma(xc0, w1,
                __builtin_elementwise_fma(e00, w2, __builtin_elementwise_fma(e10, w3, bb))));
        f2 h1 = __builtin_elementwise_fma(xr1, w0, __builtin_elementwise_fma(xc1, w1,
                __builtin_elementwise_fma(e01, w2, __builtin_elementwise_fma(e11, w3, bb))));
        f2 h2 = __builtin_elementwise_fma(xr2, w0, __builtin_elementwise_fma(xc2, w1,
                __builtin_elementwise_fma(e02, w2, __builtin_elementwise_fma(e12, w3, bb))));
        f2 h3 = __builtin_elementwise_fma(xr3, w0, __builtin_elementwise_fma(xc3, w1,
                __builtin_elementwise_fma(e03, w2, __builtin_elementwise_fma(e13, w3, bb))));
        a0 = __builtin_elementwise_fma(__builtin_elementwise_max(h0, z2), vv, a0);
        a1 = __builtin_elementwise_fma(__builtin_elementwise_max(h1, z2), vv, a1);
        a2 = __builtin_elementwise_fma(__builtin_elementwise_max(h2, z2), vv, a2);
        a3 = __builtin_elementwise_fma(__builtin_elementwise_max(h3, z2), vv, a3);
    }

    f4 res;
    res.x = mk.x ? (a0.x + a0.y) : MASK_FILL;
    res.y = mk.y ? (a1.x + a1.y) : MASK_FILL;
    res.z = mk.z ? (a2.x + a2.y) : MASK_FILL;
    res.w = mk.w ? (a3.x + a3.y) : MASK_FILL;
    *reinterpret_cast<f4*>(out + e) = res;
}

extern "C" void kernel_launch(void* const* d_in, const int* in_sizes, int n_in,
                              void* d_out, int out_size, void* d_ws, size_t ws_size,
                              hipStream_t stream) {
    const float* x          = (const float*)d_in[0];
    const int*   edge_index = (const int*)d_in[1];
    const float* edge_attr  = (const float*)d_in[2];
    const int*   edge_mask  = (const int*)d_in[3];
    const float* W1 = (const float*)d_in[4];
    const float* b1 = (const float*)d_in[5];
    const float* W2 = (const float*)d_in[6];
    const float* b2 = (const float*)d_in[7];
    const float* Ws = (const float*)d_in[8];
    const float* bs = (const float*)d_in[9];
    float* out = (float*)d_out;

    const int E = out_size;  // 1,000,000
    const int threads = 256;
    const int work = (E + EPT - 1) / EPT;
    const int blocks = (work + threads - 1) / threads;
    edge_score_fused<<<blocks, threads, 0, stream>>>(
        x, edge_index, edge_attr, edge_mask, W1, b1, W2, b2, Ws, bs, out, E);
}